// Round 4
// baseline (579.985 us; speedup 1.0000x reference)
//
#include <hip/hip_runtime.h>
#include <math.h>

// Problem constants
#define BATCH 64
#define LDIM  256
#define HDIM  1024
#define DDIM  1024
#define BAND  16
#define MNZ   33          // 2*BAND+1
#define NN    (DDIM*MNZ)  // 33792
#define RTILE 64          // k3 rows per block
#define LSTR  34          // k3 LDS row stride (pad 33->34)

#define R2 8              // DIAGNOSTIC reps on k2 (idempotent); drop next round

typedef float  v4f    __attribute__((ext_vector_type(4)));
typedef float  f32x4  __attribute__((ext_vector_type(4)));
typedef short  bf16x8 __attribute__((ext_vector_type(8)));
typedef unsigned short u16x8 __attribute__((ext_vector_type(8)));

static __device__ __forceinline__ unsigned short f2bf(float x) {
    union { float f; unsigned int u; } a; a.f = x;
    unsigned int r = a.u + 0x7fffu + ((a.u >> 16) & 1u);
    return (unsigned short)(r >> 16);
}

#define GLDS16(g, l)                                                         \
    __builtin_amdgcn_global_load_lds(                                        \
        (const __attribute__((address_space(1))) void*)(g),                  \
        (__attribute__((address_space(3))) void*)(l), 16, 0, 0)

// ---------------------------------------------------------------------------
// K1: h = gelu(z @ W1 + b1), written PRE-FRAGMENTED for K2's MFMA A-operand:
//   hb_frag[(s*4 + mt)*64 + kq*16 + nl] = bf16x8 of h[mt*16+nl][s*32+kq*8 .. +8]
// ---------------------------------------------------------------------------
__global__ __launch_bounds__(256) void k1_h(const float* __restrict__ z,
                                            const float* __restrict__ W1,
                                            const float* __restrict__ b1,
                                            unsigned short* __restrict__ hb) {
    __shared__ float zs[2][LDIM];
    const int t = threadIdx.x;
    const int b0 = blockIdx.x * 2;
    zs[0][t] = z[b0 * LDIM + t];
    zs[1][t] = z[(b0 + 1) * LDIM + t];
    __syncthreads();

    const int gid = blockIdx.x * 256 + t;
    const int b  = gid >> 7;          // batch row
    const int j8 = gid & 127;         // 8-col group
    const int j0 = j8 * 8;
    const float* __restrict__ zr = zs[t >> 7];

    float a[8];
#pragma unroll
    for (int c = 0; c < 8; ++c) a[c] = b1[j0 + c];
#pragma unroll 4
    for (int l = 0; l < LDIM; ++l) {
        const v4f w0 = *(const v4f*)&W1[(size_t)l * HDIM + j0];
        const v4f w1 = *(const v4f*)&W1[(size_t)l * HDIM + j0 + 4];
        const float zv = zr[l];
#pragma unroll
        for (int c = 0; c < 4; ++c) { a[c] = fmaf(zv, w0[c], a[c]); a[4 + c] = fmaf(zv, w1[c], a[4 + c]); }
    }
    u16x8 pk;
#pragma unroll
    for (int c = 0; c < 8; ++c) {
        const float g = 0.5f * a[c] * (1.0f + erff(a[c] * 0.70710678118654752f));
        pk[c] = f2bf(g);
    }
    const int s  = j8 >> 2;
    const int kq = j8 & 3;
    const int mt = b >> 4;
    const int nl = b & 15;
    ((u16x8*)hb)[(s * 4 + mt) * 64 + kq * 16 + nl] = pk;
}

// ---------------------------------------------------------------------------
// K2 v4: v = h @ W2 + b2, bf16 MFMA 16x16x32. 528 blocks x 4 waves, BN=64.
// T3/T4 pattern: 4-slot LDS ring (B 8KB + A 4KB per slot = 48KB), depth-3
// stage pipeline via global_load_lds, raw s_barrier + COUNTED vmcnt(6)
// (never 0 in main loop -> prefetches stay in flight across barriers; the
// v3 __syncthreads drained vmcnt(0) per step = full HBM latency per step).
// All global traffic is GLDS16 (3/wave/step: 2xB, 1xA) -> one vmcnt domain,
// no compiler-inserted draining waits. A read back via ds_read_b128.
// ---------------------------------------------------------------------------
__global__ __launch_bounds__(256) void k2_v(const float* __restrict__ W2,
                                            const float* __restrict__ b2,
                                            const unsigned short* __restrict__ hb,
                                            float* __restrict__ v) {
    __shared__ __align__(16) float          bt[4][32 * 64];   // 4 x 8 KB
    __shared__ __align__(16) unsigned short at[4][4 * 512];   // 4 x 4 KB
    const int tid  = threadIdx.x;
    const int lane = tid & 63;
    const int w    = __builtin_amdgcn_readfirstlane(tid >> 6);
    const int c0   = blockIdx.x * 64;
    const int kq   = lane >> 4;          // 0..3
    const int nl   = lane & 15;          // 0..15

    // B staging: q in {0,1}; lane l -> row q*16 + 4w + (l>>4), cols (l&15)*4..+3
    const float* __restrict__ gB =
        W2 + (size_t)(4 * w + (lane >> 4)) * NN + c0 + (lane & 15) * 4;
    // A staging: u16x8 frag index s*256 + w*64 + lane (1 KB per wave per step)
    const u16x8* __restrict__ gA = (const u16x8*)hb + w * 64 + lane;

    f32x4 acc[4];

    auto stage = [&](int slot, int s) {
        GLDS16(gB + (size_t)(s * 32) * NN,      &bt[slot][(4 * w) * 64]);
        GLDS16(gB + (size_t)(s * 32 + 16) * NN, &bt[slot][(16 + 4 * w) * 64]);
        GLDS16(gA + (size_t)s * 256,            &at[slot][w * 512]);
    };
    auto compute = [&](int slot) {
        bf16x8 af[4];
#pragma unroll
        for (int mt = 0; mt < 4; ++mt)
            af[mt] = *(const bf16x8*)&at[slot][mt * 512 + lane * 8];
        float wv[8];
#pragma unroll
        for (int j = 0; j < 8; ++j)
            wv[j] = bt[slot][(kq * 8 + j) * 64 + w * 16 + nl];
        bf16x8 bfr;
#pragma unroll
        for (int j = 0; j < 8; ++j) bfr[j] = (short)f2bf(wv[j]);
#pragma unroll
        for (int mt = 0; mt < 4; ++mt)
            acc[mt] = __builtin_amdgcn_mfma_f32_16x16x32_bf16(
                af[mt], bfr, acc[mt], 0, 0, 0);
    };

#pragma unroll 1
    for (int rep = 0; rep < R2; ++rep) {
        asm volatile("" ::: "memory");   // keep reps resident (rule #17)

#pragma unroll
        for (int mt = 0; mt < 4; ++mt) acc[mt] = (f32x4){0.f, 0.f, 0.f, 0.f};

        stage(0, 0); stage(1, 1); stage(2, 2);   // depth-3 prologue (9 loads)

#pragma unroll 1
        for (int s = 0; s <= 28; ++s) {
            asm volatile("s_waitcnt vmcnt(6)" ::: "memory");  // own stage(s) done
            __builtin_amdgcn_s_barrier();                     // all waves' too
            compute(s & 3);
            stage((s + 3) & 3, s + 3);   // overwrites slot consumed at s-1: safe
        }
        // tail: s = 29, 30, 31 (no more stages to issue)
        asm volatile("s_waitcnt vmcnt(6)" ::: "memory");
        __builtin_amdgcn_s_barrier();
        compute(29 & 3);
        asm volatile("s_waitcnt vmcnt(3)" ::: "memory");
        __builtin_amdgcn_s_barrier();
        compute(30 & 3);
        asm volatile("s_waitcnt vmcnt(0)" ::: "memory");
        __builtin_amdgcn_s_barrier();
        compute(31 & 3);

        // epilogue: C[m = mt*16 + kq*4 + r][n = c0 + w*16 + nl]
        const int col = c0 + w * 16 + nl;
        const float bias = b2[col];
        float* __restrict__ vo = v + col;
#pragma unroll
        for (int mt = 0; mt < 4; ++mt)
#pragma unroll
            for (int r = 0; r < 4; ++r)
                vo[(size_t)(mt * 16 + kq * 4 + r) * NN] = acc[mt][r] + bias;
        // rep boundary safe: next prologue writes slots 0-2; slowest wave is in
        // slot 3 (s=31), and slot overwrite hazards are barrier-ordered.
    }
}

// ---------------------------------------------------------------------------
// K3: unchanged (holds the cross-round algebra fixed).
// ---------------------------------------------------------------------------
__global__ __launch_bounds__(256) void k3_out(const float* __restrict__ v,
                                              float* __restrict__ out) {
    const int tid  = threadIdx.x;
    const int tile = blockIdx.x & (DDIM / RTILE - 1);
    const int b    = blockIdx.x / (DDIM / RTILE);
    const int i0 = tile * RTILE;
    const int js = (i0 >= BAND) ? (i0 - BAND) : 0;
    const int je = (i0 + RTILE + BAND <= DDIM) ? (i0 + RTILE + BAND) : DDIM;
    const int nelem = (je - js) * MNZ;                   // <= 3168

    __shared__ float ls[(RTILE + 2 * BAND) * LSTR];      // 12.75 KB

    const float* __restrict__ vb = v + (size_t)b * NN + (size_t)js * MNZ;
    for (int idx = tid; idx < nelem; idx += 256) {
        const int r = idx / MNZ;
        const int m = idx - r * MNZ;
        ls[r * LSTR + m] = vb[idx];
    }
    __syncthreads();

    const int j0 = tid * 4;
#pragma unroll 2
    for (int r = 0; r < RTILE; ++r) {
        const int i = i0 + r;
        v4f res = (v4f){0.f, 0.f, 0.f, 0.f};
        if (j0 + 3 >= i - BAND && j0 <= i + BAND) {
            const int lo_i = (i > BAND) ? (i - BAND) : 0;
#pragma unroll
            for (int c = 0; c < 4; ++c) {
                const int j = j0 + c;
                const int d = j - i;
                float x = 0.0f;
                if (d >= -BAND && d <= BAND) {
                    const int lo_j = (j > BAND) ? (j - BAND) : 0;
                    x = 0.5f * (ls[(i - js) * LSTR + (j - lo_i)] +
                                ls[(j - js) * LSTR + (i - lo_j)]);
                    if (d == 0) x += 1.0f;
                }
                res[c] = x;
            }
        }
        v4f* dst = ((v4f*)out) + ((size_t)b * DDIM + i) * (DDIM / 4) + tid;
        __builtin_nontemporal_store(res, dst);
    }
}

// ---------------------------------------------------------------------------
extern "C" void kernel_launch(void* const* d_in, const int* in_sizes, int n_in,
                              void* d_out, int out_size, void* d_ws, size_t ws_size,
                              hipStream_t stream) {
    const float* z  = (const float*)d_in[0];
    const float* W1 = (const float*)d_in[2];
    const float* b1 = (const float*)d_in[3];
    const float* W2 = (const float*)d_in[4];
    const float* b2 = (const float*)d_in[5];

    unsigned short* hb = (unsigned short*)d_ws;          // 128 KB (fragmented h)
    float* v = (float*)((char*)d_ws + (size_t)BATCH * HDIM * sizeof(unsigned short));
    float* out = (float*)d_out;

    k1_h  <<<dim3(BATCH / 2), 256, 0, stream>>>(z, W1, b1, hb);
    k2_v  <<<dim3(NN / 64), 256, 0, stream>>>(W2, b2, hb, v);
    k3_out<<<dim3(BATCH * (DDIM / RTILE)), 256, 0, stream>>>(v, out);
}

// Round 5
// 433.180 us; speedup vs baseline: 1.3389x; 1.3389x over previous
//
#include <hip/hip_runtime.h>
#include <math.h>

// Problem constants
#define BATCH 64
#define LDIM  256
#define HDIM  1024
#define DDIM  1024
#define BAND  16
#define MNZ   33          // 2*BAND+1
#define NN    (DDIM*MNZ)  // 33792
#define RTILE 64          // k3 rows per block
#define LSTR  34          // k3 LDS row stride (pad 33->34)

typedef float  v4f    __attribute__((ext_vector_type(4)));
typedef float  f32x4  __attribute__((ext_vector_type(4)));
typedef short  bf16x8 __attribute__((ext_vector_type(8)));
typedef unsigned short u16x8 __attribute__((ext_vector_type(8)));

static __device__ __forceinline__ unsigned short f2bf(float x) {
    union { float f; unsigned int u; } a; a.f = x;
    unsigned int r = a.u + 0x7fffu + ((a.u >> 16) & 1u);
    return (unsigned short)(r >> 16);
}

#define GLDS16(g, l)                                                         \
    __builtin_amdgcn_global_load_lds(                                        \
        (const __attribute__((address_space(1))) void*)(g),                  \
        (__attribute__((address_space(3))) void*)(l), 16, 0, 0)

// ---------------------------------------------------------------------------
// K1: h = gelu(z @ W1 + b1), written PRE-FRAGMENTED for K2's MFMA A-operand:
//   hb_frag[(s*4 + mt)*64 + kq*16 + nl] = bf16x8 of h[mt*16+nl][s*32+kq*8 .. +8]
// ---------------------------------------------------------------------------
__global__ __launch_bounds__(256) void k1_h(const float* __restrict__ z,
                                            const float* __restrict__ W1,
                                            const float* __restrict__ b1,
                                            unsigned short* __restrict__ hb) {
    __shared__ float zs[2][LDIM];
    const int t = threadIdx.x;
    const int b0 = blockIdx.x * 2;
    zs[0][t] = z[b0 * LDIM + t];
    zs[1][t] = z[(b0 + 1) * LDIM + t];
    __syncthreads();

    const int gid = blockIdx.x * 256 + t;
    const int b  = gid >> 7;          // batch row
    const int j8 = gid & 127;         // 8-col group
    const int j0 = j8 * 8;
    const float* __restrict__ zr = zs[t >> 7];

    float a[8];
#pragma unroll
    for (int c = 0; c < 8; ++c) a[c] = b1[j0 + c];
#pragma unroll 4
    for (int l = 0; l < LDIM; ++l) {
        const v4f w0 = *(const v4f*)&W1[(size_t)l * HDIM + j0];
        const v4f w1 = *(const v4f*)&W1[(size_t)l * HDIM + j0 + 4];
        const float zv = zr[l];
#pragma unroll
        for (int c = 0; c < 4; ++c) { a[c] = fmaf(zv, w0[c], a[c]); a[4 + c] = fmaf(zv, w1[c], a[4 + c]); }
    }
    u16x8 pk;
#pragma unroll
    for (int c = 0; c < 8; ++c) {
        const float g = 0.5f * a[c] * (1.0f + erff(a[c] * 0.70710678118654752f));
        pk[c] = f2bf(g);
    }
    const int s  = j8 >> 2;
    const int kq = j8 & 3;
    const int mt = b >> 4;
    const int nl = b & 15;
    ((u16x8*)hb)[(s * 4 + mt) * 64 + kq * 16 + nl] = pk;
}

// ---------------------------------------------------------------------------
// K2 v5: v = h @ W2 + b2, bf16 MFMA 16x16x32. 528 blocks x 4 waves, BN=64.
// 4-slot LDS ring, depth-3 global_load_lds pipeline, raw s_barrier + counted
// vmcnt(6) (never 0 in main loop). Measured r4: 26.6 us/rep, 8.65M LDS bank
// conflicts (B-read 4-way: bank indep. of row). v5 adds the row-XOR swizzle,
// rule-#21 style: LINEAR LDS dest, PRE-SWIZZLED global source (col-chunk
// ^= ((w>>1)&1)<<2 -- wave-uniform: staged-row bit3 == w>>1), and the
// matching XOR on the read (col ^= (kq&1)<<4 -- read-row bit3 == kq&1).
// kq{0,2} vs {1,3} now hit different banks -> 2-way (free, m136).
// ---------------------------------------------------------------------------
__global__ __launch_bounds__(256) void k2_v(const float* __restrict__ W2,
                                            const float* __restrict__ b2,
                                            const unsigned short* __restrict__ hb,
                                            float* __restrict__ v) {
    __shared__ __align__(16) float          bt[4][32 * 64];   // 4 x 8 KB
    __shared__ __align__(16) unsigned short at[4][4 * 512];   // 4 x 4 KB
    const int tid  = threadIdx.x;
    const int lane = tid & 63;
    const int w    = __builtin_amdgcn_readfirstlane(tid >> 6);
    const int c0   = blockIdx.x * 64;
    const int kq   = lane >> 4;          // 0..3
    const int nl   = lane & 15;          // 0..15

    // B staging: lane l -> row q*16 + 4w + (l>>4); SOURCE col-chunk swizzled.
    const int cg = (lane & 15) ^ (((w >> 1) & 1) << 2);   // pre-swizzled source
    const float* __restrict__ gB =
        W2 + (size_t)(4 * w + (lane >> 4)) * NN + c0 + cg * 4;
    // A staging: u16x8 frag index s*256 + w*64 + lane (1 KB per wave per step)
    const u16x8* __restrict__ gA = (const u16x8*)hb + w * 64 + lane;

    f32x4 acc[4];
#pragma unroll
    for (int mt = 0; mt < 4; ++mt) acc[mt] = (f32x4){0.f, 0.f, 0.f, 0.f};

    auto stage = [&](int slot, int s) {
        GLDS16(gB + (size_t)(s * 32) * NN,      &bt[slot][(4 * w) * 64]);
        GLDS16(gB + (size_t)(s * 32 + 16) * NN, &bt[slot][(16 + 4 * w) * 64]);
        GLDS16(gA + (size_t)s * 256,            &at[slot][w * 512]);
    };
    // read col: n ^ swz(row); row = kq*8+j has bit3 == kq&1
    const int rcol = (w * 16 + nl) ^ ((kq & 1) << 4);
    auto compute = [&](int slot) {
        bf16x8 af[4];
#pragma unroll
        for (int mt = 0; mt < 4; ++mt)
            af[mt] = *(const bf16x8*)&at[slot][mt * 512 + lane * 8];
        float wv[8];
#pragma unroll
        for (int j = 0; j < 8; ++j)
            wv[j] = bt[slot][(kq * 8 + j) * 64 + rcol];
        bf16x8 bfr;
#pragma unroll
        for (int j = 0; j < 8; ++j) bfr[j] = (short)f2bf(wv[j]);
#pragma unroll
        for (int mt = 0; mt < 4; ++mt)
            acc[mt] = __builtin_amdgcn_mfma_f32_16x16x32_bf16(
                af[mt], bfr, acc[mt], 0, 0, 0);
    };

    stage(0, 0); stage(1, 1); stage(2, 2);   // depth-3 prologue (9 loads)

#pragma unroll 1
    for (int s = 0; s <= 28; ++s) {
        asm volatile("s_waitcnt vmcnt(6)" ::: "memory");  // own stage(s) done
        __builtin_amdgcn_s_barrier();                     // all waves' too
        compute(s & 3);
        stage((s + 3) & 3, s + 3);   // overwrites slot consumed at s-1: safe
    }
    // tail: s = 29, 30, 31 (no more stages to issue)
    asm volatile("s_waitcnt vmcnt(6)" ::: "memory");
    __builtin_amdgcn_s_barrier();
    compute(29 & 3);
    asm volatile("s_waitcnt vmcnt(3)" ::: "memory");
    __builtin_amdgcn_s_barrier();
    compute(30 & 3);
    asm volatile("s_waitcnt vmcnt(0)" ::: "memory");
    __builtin_amdgcn_s_barrier();
    compute(31 & 3);

    // epilogue: C[m = mt*16 + kq*4 + r][n = c0 + w*16 + nl]
    const int col = c0 + w * 16 + nl;
    const float bias = b2[col];
    float* __restrict__ vo = v + col;
#pragma unroll
    for (int mt = 0; mt < 4; ++mt)
#pragma unroll
        for (int r = 0; r < 4; ++r)
            vo[(size_t)(mt * 16 + kq * 4 + r) * NN] = acc[mt][r] + bias;
}

// ---------------------------------------------------------------------------
// K3: at its write roofline (~44.5 us vs 43 floor for the 268 MB output).
// block = (batch b, 64-row tile); stage v rows [i0-16, i0+80) in LDS; 64 rows
// of float4 NT stores.
// ---------------------------------------------------------------------------
__global__ __launch_bounds__(256) void k3_out(const float* __restrict__ v,
                                              float* __restrict__ out) {
    const int tid  = threadIdx.x;
    const int tile = blockIdx.x & (DDIM / RTILE - 1);
    const int b    = blockIdx.x / (DDIM / RTILE);
    const int i0 = tile * RTILE;
    const int js = (i0 >= BAND) ? (i0 - BAND) : 0;
    const int je = (i0 + RTILE + BAND <= DDIM) ? (i0 + RTILE + BAND) : DDIM;
    const int nelem = (je - js) * MNZ;                   // <= 3168

    __shared__ float ls[(RTILE + 2 * BAND) * LSTR];      // 12.75 KB

    const float* __restrict__ vb = v + (size_t)b * NN + (size_t)js * MNZ;
    for (int idx = tid; idx < nelem; idx += 256) {
        const int r = idx / MNZ;
        const int m = idx - r * MNZ;
        ls[r * LSTR + m] = vb[idx];
    }
    __syncthreads();

    const int j0 = tid * 4;
#pragma unroll 2
    for (int r = 0; r < RTILE; ++r) {
        const int i = i0 + r;
        v4f res = (v4f){0.f, 0.f, 0.f, 0.f};
        if (j0 + 3 >= i - BAND && j0 <= i + BAND) {
            const int lo_i = (i > BAND) ? (i - BAND) : 0;
#pragma unroll
            for (int c = 0; c < 4; ++c) {
                const int j = j0 + c;
                const int d = j - i;
                float x = 0.0f;
                if (d >= -BAND && d <= BAND) {
                    const int lo_j = (j > BAND) ? (j - BAND) : 0;
                    x = 0.5f * (ls[(i - js) * LSTR + (j - lo_i)] +
                                ls[(j - js) * LSTR + (i - lo_j)]);
                    if (d == 0) x += 1.0f;
                }
                res[c] = x;
            }
        }
        v4f* dst = ((v4f*)out) + ((size_t)b * DDIM + i) * (DDIM / 4) + tid;
        __builtin_nontemporal_store(res, dst);
    }
}

// ---------------------------------------------------------------------------
extern "C" void kernel_launch(void* const* d_in, const int* in_sizes, int n_in,
                              void* d_out, int out_size, void* d_ws, size_t ws_size,
                              hipStream_t stream) {
    const float* z  = (const float*)d_in[0];
    const float* W1 = (const float*)d_in[2];
    const float* b1 = (const float*)d_in[3];
    const float* W2 = (const float*)d_in[4];
    const float* b2 = (const float*)d_in[5];

    unsigned short* hb = (unsigned short*)d_ws;          // 128 KB (fragmented h)
    float* v = (float*)((char*)d_ws + (size_t)BATCH * HDIM * sizeof(unsigned short));
    float* out = (float*)d_out;

    k1_h  <<<dim3(BATCH / 2), 256, 0, stream>>>(z, W1, b1, hb);
    k2_v  <<<dim3(NN / 64), 256, 0, stream>>>(W2, b2, hb, v);
    k3_out<<<dim3(BATCH * (DDIM / RTILE)), 256, 0, stream>>>(v, out);
}

// Round 6
// 426.711 us; speedup vs baseline: 1.3592x; 1.0152x over previous
//
#include <hip/hip_runtime.h>
#include <math.h>

// Problem constants
#define BATCH 64
#define LDIM  256
#define HDIM  1024
#define DDIM  1024
#define BAND  16
#define MNZ   33          // 2*BAND+1
#define NN    (DDIM*MNZ)  // 33792
#define RTILE 64          // k3 rows per block
#define LSTR  34          // k3 LDS row stride (pad 33->34)

typedef float  v4f    __attribute__((ext_vector_type(4)));
typedef float  f32x4  __attribute__((ext_vector_type(4)));
typedef short  bf16x8 __attribute__((ext_vector_type(8)));
typedef unsigned short u16x8 __attribute__((ext_vector_type(8)));

static __device__ __forceinline__ unsigned short f2bf(float x) {
    union { float f; unsigned int u; } a; a.f = x;
    unsigned int r = a.u + 0x7fffu + ((a.u >> 16) & 1u);
    return (unsigned short)(r >> 16);
}

#define GLDS16(g, l)                                                         \
    __builtin_amdgcn_global_load_lds(                                        \
        (const __attribute__((address_space(1))) void*)(g),                  \
        (__attribute__((address_space(3))) void*)(l), 16, 0, 0)

// ---------------------------------------------------------------------------
// K1: h = gelu(z @ W1 + b1), written PRE-FRAGMENTED for K2's MFMA A-operand:
//   hb_frag[(s*4 + mt)*64 + kq*16 + nl] = bf16x8 of h[mt*16+nl][s*32+kq*8 .. +8]
// ---------------------------------------------------------------------------
__global__ __launch_bounds__(256) void k1_h(const float* __restrict__ z,
                                            const float* __restrict__ W1,
                                            const float* __restrict__ b1,
                                            unsigned short* __restrict__ hb) {
    __shared__ float zs[2][LDIM];
    const int t = threadIdx.x;
    const int b0 = blockIdx.x * 2;
    zs[0][t] = z[b0 * LDIM + t];
    zs[1][t] = z[(b0 + 1) * LDIM + t];
    __syncthreads();

    const int gid = blockIdx.x * 256 + t;
    const int b  = gid >> 7;          // batch row
    const int j8 = gid & 127;         // 8-col group
    const int j0 = j8 * 8;
    const float* __restrict__ zr = zs[t >> 7];

    float a[8];
#pragma unroll
    for (int c = 0; c < 8; ++c) a[c] = b1[j0 + c];
#pragma unroll 4
    for (int l = 0; l < LDIM; ++l) {
        const v4f w0 = *(const v4f*)&W1[(size_t)l * HDIM + j0];
        const v4f w1 = *(const v4f*)&W1[(size_t)l * HDIM + j0 + 4];
        const float zv = zr[l];
#pragma unroll
        for (int c = 0; c < 4; ++c) { a[c] = fmaf(zv, w0[c], a[c]); a[4 + c] = fmaf(zv, w1[c], a[4 + c]); }
    }
    u16x8 pk;
#pragma unroll
    for (int c = 0; c < 8; ++c) {
        const float g = 0.5f * a[c] * (1.0f + erff(a[c] * 0.70710678118654752f));
        pk[c] = f2bf(g);
    }
    const int s  = j8 >> 2;
    const int kq = j8 & 3;
    const int mt = b >> 4;
    const int nl = b & 15;
    ((u16x8*)hb)[(s * 4 + mt) * 64 + kq * 16 + nl] = pk;
}

// ---------------------------------------------------------------------------
// K2 v6: v = h @ W2 + b2, bf16 MFMA 16x16x32. BN=256 FOR FETCH CONTIGUITY.
// Cold-state diagnosis (r0/r3/r5 invariance + r4 rep-avg): per-row W2 reads
// of 256B @ stride 135KB stream at only ~2 TB/s; schedule changes were all
// null. BN=256 -> 1KB contiguous per row visit (one GLDS16 = one full row).
// 132 blocks x 4 waves; wave owns 64 cols (4x4 MFMA tiles, acc[4][4]).
// Ring-4 LDS slots (4 x 32KB B + 4 x 4KB A = 144KB, 1 block/CU), depth-3
// counted-vmcnt pipeline: 9 GLDS16/wave/step (8 B rows + 1 A frag), wait
// vmcnt(18) in main loop (never 0), tail 18/9/0. BW check: 4 waves x 27KB
// outstanding = 108KB/CU >> 18KB Little's-law need at 132 CUs.
// Swizzle (rule #21, both-sides): source col 4*(lane ^ ((w&1)<<2)) [staged
// row bit3 == w&1, wave-uniform], read col ^ ((kq&1)<<4) [row bit3 == kq&1]
// -> 2-way bank access (free).
// ---------------------------------------------------------------------------
__global__ __launch_bounds__(256) void k2_v(const float* __restrict__ W2,
                                            const float* __restrict__ b2,
                                            const unsigned short* __restrict__ hb,
                                            float* __restrict__ v) {
    __shared__ __align__(16) float          bt[4][32 * 256];   // 128 KB
    __shared__ __align__(16) unsigned short at4[4][4 * 512];   // 16 KB
    const int tid  = threadIdx.x;
    const int lane = tid & 63;
    const int w    = __builtin_amdgcn_readfirstlane(tid >> 6);
    const int c0   = blockIdx.x * 256;
    const int kq   = lane >> 4;          // 0..3
    const int nl   = lane & 15;          // 0..15

    // B source: wave w stages rows w*8+i of each K-step; one GLDS16 covers a
    // full 256-float row (lane-> col 4*(lane ^ ((w&1)<<2)), pre-swizzled).
    const int scol = 4 * (lane ^ ((w & 1) << 2));
    const float* __restrict__ gB = W2 + (size_t)(w * 8) * NN + c0 + scol;
    // A source: wave w stages frag mt=w: (s*4 + w)*64 + lane (u16x8 units)
    const u16x8* __restrict__ gA = (const u16x8*)hb + w * 64 + lane;

    f32x4 acc[4][4];
#pragma unroll
    for (int mt = 0; mt < 4; ++mt)
#pragma unroll
        for (int nt = 0; nt < 4; ++nt)
            acc[mt][nt] = (f32x4){0.f, 0.f, 0.f, 0.f};

    auto stage = [&](int slot, int s) {
#pragma unroll
        for (int i = 0; i < 8; ++i)
            GLDS16(gB + (size_t)(s * 32 + i) * NN, &bt[slot][(w * 8 + i) * 256]);
        GLDS16(gA + (size_t)s * 256, &at4[slot][w * 512]);
    };
    auto compute = [&](int slot) {
        bf16x8 af[4];
#pragma unroll
        for (int mt = 0; mt < 4; ++mt)
            af[mt] = *(const bf16x8*)&at4[slot][mt * 512 + lane * 8];
        bf16x8 bfr[4];
#pragma unroll
        for (int nt = 0; nt < 4; ++nt) {
            const int rc = (w * 64 + nt * 16 + nl) ^ ((kq & 1) << 4);
            float wv[8];
#pragma unroll
            for (int j = 0; j < 8; ++j)
                wv[j] = bt[slot][(kq * 8 + j) * 256 + rc];
#pragma unroll
            for (int j = 0; j < 8; ++j) bfr[nt][j] = (short)f2bf(wv[j]);
        }
#pragma unroll
        for (int mt = 0; mt < 4; ++mt)
#pragma unroll
            for (int nt = 0; nt < 4; ++nt)
                acc[mt][nt] = __builtin_amdgcn_mfma_f32_16x16x32_bf16(
                    af[mt], bfr[nt], acc[mt][nt], 0, 0, 0);
    };

    stage(0, 0); stage(1, 1); stage(2, 2);   // depth-3 prologue (27 loads/wave)

#pragma unroll 1
    for (int s = 0; s <= 28; ++s) {
        asm volatile("s_waitcnt vmcnt(18)" ::: "memory"); // own slot-s loads done
        __builtin_amdgcn_s_barrier();                     // all waves' slot-s done
        compute(s & 3);
        stage((s + 3) & 3, s + 3);   // slot (s+3)&3 last read at step s-1: safe
    }
    // tail: s = 29, 30, 31 (no more stages)
    asm volatile("s_waitcnt vmcnt(18)" ::: "memory");
    __builtin_amdgcn_s_barrier();
    compute(29 & 3);
    asm volatile("s_waitcnt vmcnt(9)" ::: "memory");
    __builtin_amdgcn_s_barrier();
    compute(30 & 3);
    asm volatile("s_waitcnt vmcnt(0)" ::: "memory");
    __builtin_amdgcn_s_barrier();
    compute(31 & 3);

    // epilogue: C[m = mt*16 + kq*4 + r][n = c0 + w*64 + nt*16 + nl]
    const int colb = c0 + w * 64;
#pragma unroll
    for (int nt = 0; nt < 4; ++nt) {
        const int col = colb + nt * 16 + nl;
        const float bias = b2[col];
        float* __restrict__ vo = v + col;
#pragma unroll
        for (int mt = 0; mt < 4; ++mt)
#pragma unroll
            for (int r = 0; r < 4; ++r)
                vo[(size_t)(mt * 16 + kq * 4 + r) * NN] = acc[mt][nt][r] + bias;
    }
}

// ---------------------------------------------------------------------------
// K3: at its write roofline (~44.5 us vs 43 floor for the 268 MB output).
// ---------------------------------------------------------------------------
__global__ __launch_bounds__(256) void k3_out(const float* __restrict__ v,
                                              float* __restrict__ out) {
    const int tid  = threadIdx.x;
    const int tile = blockIdx.x & (DDIM / RTILE - 1);
    const int b    = blockIdx.x / (DDIM / RTILE);
    const int i0 = tile * RTILE;
    const int js = (i0 >= BAND) ? (i0 - BAND) : 0;
    const int je = (i0 + RTILE + BAND <= DDIM) ? (i0 + RTILE + BAND) : DDIM;
    const int nelem = (je - js) * MNZ;                   // <= 3168

    __shared__ float ls[(RTILE + 2 * BAND) * LSTR];      // 12.75 KB

    const float* __restrict__ vb = v + (size_t)b * NN + (size_t)js * MNZ;
    for (int idx = tid; idx < nelem; idx += 256) {
        const int r = idx / MNZ;
        const int m = idx - r * MNZ;
        ls[r * LSTR + m] = vb[idx];
    }
    __syncthreads();

    const int j0 = tid * 4;
#pragma unroll 2
    for (int r = 0; r < RTILE; ++r) {
        const int i = i0 + r;
        v4f res = (v4f){0.f, 0.f, 0.f, 0.f};
        if (j0 + 3 >= i - BAND && j0 <= i + BAND) {
            const int lo_i = (i > BAND) ? (i - BAND) : 0;
#pragma unroll
            for (int c = 0; c < 4; ++c) {
                const int j = j0 + c;
                const int d = j - i;
                float x = 0.0f;
                if (d >= -BAND && d <= BAND) {
                    const int lo_j = (j > BAND) ? (j - BAND) : 0;
                    x = 0.5f * (ls[(i - js) * LSTR + (j - lo_i)] +
                                ls[(j - js) * LSTR + (i - lo_j)]);
                    if (d == 0) x += 1.0f;
                }
                res[c] = x;
            }
        }
        v4f* dst = ((v4f*)out) + ((size_t)b * DDIM + i) * (DDIM / 4) + tid;
        __builtin_nontemporal_store(res, dst);
    }
}

// ---------------------------------------------------------------------------
extern "C" void kernel_launch(void* const* d_in, const int* in_sizes, int n_in,
                              void* d_out, int out_size, void* d_ws, size_t ws_size,
                              hipStream_t stream) {
    const float* z  = (const float*)d_in[0];
    const float* W1 = (const float*)d_in[2];
    const float* b1 = (const float*)d_in[3];
    const float* W2 = (const float*)d_in[4];
    const float* b2 = (const float*)d_in[5];

    unsigned short* hb = (unsigned short*)d_ws;          // 128 KB (fragmented h)
    float* v = (float*)((char*)d_ws + (size_t)BATCH * HDIM * sizeof(unsigned short));
    float* out = (float*)d_out;

    k1_h  <<<dim3(BATCH / 2), 256, 0, stream>>>(z, W1, b1, hb);
    k2_v  <<<dim3(NN / 256), 256, 0, stream>>>(W2, b2, hb, v);
    k3_out<<<dim3(BATCH * (DDIM / RTILE)), 256, 0, stream>>>(v, out);
}